// Round 2
// baseline (356.800 us; speedup 1.0000x reference)
//
#include <hip/hip_runtime.h>

// Problem constants
#define Bsz 16384
#define Isz 512
#define Hsz 512
#define Ksz 1024   // I + H
#define N4H 2048   // 4*H

// GEMM tile (256x256, 8-phase schedule)
#define BM 256
#define BN 256
#define BK 64

typedef __bf16 bf16x8 __attribute__((ext_vector_type(8)));
typedef __bf16 bf16x4 __attribute__((ext_vector_type(4)));
typedef float  f32x4  __attribute__((ext_vector_type(4)));

__device__ __forceinline__ void async_copy16(const void* g, void* l) {
    __builtin_amdgcn_global_load_lds(
        (__attribute__((address_space(1))) void*)g,
        (__attribute__((address_space(3))) void*)l,
        16, 0, 0);
}

// ---------------------------------------------------------------------------
// Combined pack kernel (unchanged).
// Blocks [0, 16384): activations  Aq[b][k] = bf16([input|h_prev][b][k])
// Blocks [16384, 18432): weights with gate-interleaved row permutation +
//   fused bias.  Permuted row p: nb=p/128, n=p%128; wn=n>>6, gate=(n>>4)&3,
//   c=n&15 -> original row = gate*512 + nb*32 + wn*16 + c.
// ---------------------------------------------------------------------------
__global__ void pack_all(const float* __restrict__ x, const float* __restrict__ h,
                         const float* __restrict__ Wxh, const float* __restrict__ Whh,
                         const float* __restrict__ bxh, const float* __restrict__ bhh,
                         __bf16* __restrict__ Aq, __bf16* __restrict__ Bq,
                         float* __restrict__ bias) {
    if (blockIdx.x < 16384) {
        int idx = blockIdx.x * 256 + threadIdx.x;
        int e   = idx << 2;
        int row = e >> 10, col = e & 1023;
        const float4 v = (col < Isz)
            ? *(const float4*)(x + (size_t)row * Isz + col)
            : *(const float4*)(h + (size_t)row * Hsz + (col - Isz));
        bf16x4 o = { (__bf16)v.x, (__bf16)v.y, (__bf16)v.z, (__bf16)v.w };
        *(bf16x4*)(Aq + (size_t)e) = o;
    } else {
        int idx = (blockIdx.x - 16384) * 256 + threadIdx.x;
        int p   = idx >> 8;
        int k   = (idx & 255) << 2;
        int nb  = p >> 7, n = p & 127;
        int wn  = n >> 6, t = (n >> 4) & 3, c = n & 15;
        int orow = t * Hsz + nb * 32 + wn * 16 + c;
        const float4 v = (k < Isz)
            ? *(const float4*)(Wxh + (size_t)orow * Isz + k)
            : *(const float4*)(Whh + (size_t)orow * Hsz + (k - Isz));
        bf16x4 o = { (__bf16)v.x, (__bf16)v.y, (__bf16)v.z, (__bf16)v.w };
        *(bf16x4*)(Bq + (size_t)p * Ksz + k) = o;
        if ((idx & 255) == 0) bias[p] = bxh[orow] + bhh[orow];
    }
}

// ---------------------------------------------------------------------------
// Fused GEMM + sLSTM epilogue — 256x256 tile, 8-wave, 8-phase schedule.
//
// ROUND-2 CHANGE: bijective XCD-aware block remap (1-D grid of 512).
// Physical id p: x=p%8 (XCD, HW round-robin), j=(p>>3)&31, r=p>>8 (round).
//   bm = 8x + (j&3) + 4r,  nbb = j>>2.
// Per XCD per round: 4 A-panels (2 MB) + all 8 B-tiles (2 MB) = 4 MB = L2.
// B is L2-resident across both rounds; A-panels are XCD-private (fetched
// once). This keeps the ~11.6 TB/s aggregate staging demand inside L2 so
// the counted vmcnt(4) never stalls (round-1 diagnosis: staging-BW-bound,
// phase time ~3x budget).
//
// Schedule (unchanged from round 1): per phase {ds_read subtile | issue 1
// half-tile global_load_lds} -> barrier -> lgkmcnt(0) -> setprio(1) ->
// 16 MFMA -> setprio(0) -> barrier; vmcnt(4) only at phases 4 and 8.
// LDS XOR swizzle: row r group g at position g^(r&7); staging permutes the
// per-lane global SOURCE group (gload_lds LDS dest stays linear).
// ---------------------------------------------------------------------------
#define CFENCE asm volatile("" ::: "memory")
#define BARRIER { CFENCE; __builtin_amdgcn_s_barrier(); CFENCE; }
#define WAITLGKM asm volatile("s_waitcnt lgkmcnt(0)" ::: "memory")
#define WAITVM4  asm volatile("s_waitcnt vmcnt(4)" ::: "memory")

#define LDS_A(ap, fbase)                                                      \
    _Pragma("unroll") for (int f = 0; f < 4; ++f)                             \
    _Pragma("unroll") for (int kk = 0; kk < 2; ++kk)                          \
        af[f][kk] = *(const bf16x8*)((ap) + (fbase + f) * 1024 + ko[kk]);

#define LDS_B(bp, nbase)                                                      \
    _Pragma("unroll") for (int n = 0; n < 2; ++n)                             \
    _Pragma("unroll") for (int kk = 0; kk < 2; ++kk)                          \
        bf[(nbase) + n][kk] = *(const bf16x8*)((bp) + ((nbase) + n) * 1024 + ko[kk]);

#define MMA(fbase, nbase)                                                     \
    __builtin_amdgcn_s_setprio(1);                                            \
    _Pragma("unroll") for (int f = 0; f < 4; ++f)                             \
    _Pragma("unroll") for (int n = 0; n < 2; ++n)                             \
    _Pragma("unroll") for (int kk = 0; kk < 2; ++kk)                          \
        acc[(fbase) + f][(nbase) + n] = __builtin_amdgcn_mfma_f32_16x16x32_bf16( \
            af[f][kk], bf[(nbase) + n][kk], acc[(fbase) + f][(nbase) + n], 0, 0, 0); \
    __builtin_amdgcn_s_setprio(0);

// One half-tile = 128 rows x 64 cols bf16 = 16 KiB = 2 gload_lds / thread.
#define STAGE(arr, buf, half, src, step)                                      \
    { async_copy16((src) + (size_t)((half) * 128 + rrow) * Ksz + (step) * 64 + scol, \
                   (char*)(arr) + (buf) * 32768 + (half) * 16384 + tid * 16); \
      async_copy16((src) + (size_t)((half) * 128 + 64 + rrow) * Ksz + (step) * 64 + scol, \
                   (char*)(arr) + (buf) * 32768 + (half) * 16384 + 8192 + tid * 16); }

__global__ __launch_bounds__(512, 2) void slstm_gemm(
    const __bf16* __restrict__ Aq, const __bf16* __restrict__ Bq,
    const float* __restrict__ bias,
    const float* __restrict__ c_prev, const float* __restrict__ m_prev,
    const float* __restrict__ n_prev, float* __restrict__ out) {

    __shared__ __bf16 As[2][BM * BK];   // 2 x 32 KiB
    __shared__ __bf16 Bs[2][BN * BK];   // 2 x 32 KiB   (128 KiB total)

    const int tid  = threadIdx.x;
    const int w    = tid >> 6;
    const int lane = tid & 63;
    const int wm   = w & 1;          // wave M row (0..1) -> 128 rows each
    const int wc   = w >> 1;         // wave N col (0..3) -> 64 cols each

    // XCD-aware bijective remap (see header comment)
    const int pid = blockIdx.x;
    const int xcd = pid & 7;
    const int jj  = (pid >> 3) & 31;
    const int rr  = pid >> 8;
    const int bm  = xcd * 8 + (jj & 3) + rr * 4;   // batch tile (0..63)
    const int nbb = jj >> 2;                       // 256-wide gate-col tile (0..7)

    const int lr = lane & 15;
    const int g0 = lane >> 4;        // 0..3
    const int px = lr & 7;

    const __bf16* Ag = Aq + (size_t)bm  * BM * Ksz;
    const __bf16* Bg = Bq + (size_t)nbb * BN * Ksz;

    // staging geometry
    const int rrow = tid >> 3;                    // 0..63
    const int scol = ((tid & 7) ^ (rrow & 7)) * 8;

    // fragment-read bases (swizzled k-group offsets; row&7 == lr&7 always)
    const __bf16* A0p = &As[0][(wm * 128 + lr) * 64];
    const __bf16* A1p = &As[1][(wm * 128 + lr) * 64];
    const __bf16* B0p = &Bs[0][(wc * 64 + lr) * 64];
    const __bf16* B1p = &Bs[1][(wc * 64 + lr) * 64];
    const int ko[2] = { ((0 * 4 + g0) ^ px) * 8, ((1 * 4 + g0) ^ px) * 8 };

    __bf16* AsB = &As[0][0];
    __bf16* BsB = &Bs[0][0];

    f32x4 acc[8][4];
    const f32x4 zero = {0.f, 0.f, 0.f, 0.f};
#pragma unroll
    for (int mi = 0; mi < 8; ++mi)
#pragma unroll
        for (int ni = 0; ni < 4; ++ni) acc[mi][ni] = zero;

    // ---------------- prologue: stage b0 step0 fully + B(b1) step1 ----------
    STAGE(BsB, 0, 0, Bg, 0);
    STAGE(BsB, 0, 1, Bg, 0);
    STAGE(AsB, 0, 0, Ag, 0);
    STAGE(AsB, 0, 1, Ag, 0);
    STAGE(BsB, 1, 0, Bg, 1);
    STAGE(BsB, 1, 1, Bg, 1);
    WAITVM4;            // b0 step0 complete; B(b1) step1 (4 loads) in flight
    BARRIER;

    bf16x8 af[4][2];
    bf16x8 bf[4][2];

#pragma unroll 1
    for (int i = 0; i < 8; ++i) {
        const int ic  = (i < 7) ? i : 6;
        const int sA1 = 2 * i + 1;       // A(b1) for this iteration's odd step
        const int sB0 = 2 * ic + 2;      // next even step into b0 (clamped)
        const int sB1 = 2 * ic + 3;      // next odd step into b1 (clamped)

        // ---- p0 (b0, quad 0,0): read A[0..3], B[0..1] ----
        LDS_A(A0p, 0);
        LDS_B(B0p, 0);
        STAGE(AsB, 1, 0, Ag, sA1);
        BARRIER; WAITLGKM;
        MMA(0, 0);
        BARRIER;

        // ---- p1 (b0, quad 0,1): read B[2..3] ----
        LDS_B(B0p, 2);
        STAGE(AsB, 1, 1, Ag, sA1);
        BARRIER; WAITLGKM;
        MMA(0, 2);
        BARRIER;

        // ---- p2 (b0, quad 1,1): read A[4..7] ----
        LDS_A(A0p, 4);
        STAGE(BsB, 0, 0, Bg, sB0);
        BARRIER; WAITLGKM;
        MMA(4, 2);
        BARRIER;

        // ---- p3 (b0, quad 1,0): no reads (bf[0..1] live from p0) ----
        STAGE(BsB, 0, 1, Bg, sB0);
        BARRIER;
        MMA(4, 0);
        WAITVM4;         // A/B(b1) step 2i+1 complete; p2+p3 stages in flight
        BARRIER;

        // ---- p4 (b1, quad 0,0) ----
        LDS_A(A1p, 0);
        LDS_B(B1p, 0);
        STAGE(AsB, 0, 0, Ag, sB0);
        BARRIER; WAITLGKM;
        MMA(0, 0);
        BARRIER;

        // ---- p5 (b1, quad 0,1) ----
        LDS_B(B1p, 2);
        STAGE(AsB, 0, 1, Ag, sB0);
        BARRIER; WAITLGKM;
        MMA(0, 2);
        BARRIER;

        // ---- p6 (b1, quad 1,1) ----
        LDS_A(A1p, 4);
        STAGE(BsB, 1, 0, Bg, sB1);
        BARRIER; WAITLGKM;
        MMA(4, 2);
        BARRIER;

        // ---- p7 (b1, quad 1,0) ----
        STAGE(BsB, 1, 1, Bg, sB1);
        BARRIER;
        MMA(4, 0);
        WAITVM4;         // b0 step 2i+2 complete; p6+p7 stages in flight
        BARRIER;
    }

    // ---------------- fused sLSTM epilogue ----------------
    // Wave wc's 4 N-fragments are the 4 gates of the same 16 h values.
    const int hidx = (nbb * 2 + (wc >> 1)) * 32 + (wc & 1) * 16 + lr;

    float bsv[4];
#pragma unroll
    for (int n = 0; n < 4; ++n)
        bsv[n] = bias[nbb * 256 + wc * 64 + n * 16 + lr];

    const size_t BH = (size_t)Bsz * Hsz;

#pragma unroll
    for (int mi = 0; mi < 8; ++mi) {
        const int mbase = bm * 256 + wm * 128 + mi * 16 + g0 * 4;
#pragma unroll
        for (int r = 0; r < 4; ++r) {
            const int m = mbase + r;
            const size_t off = (size_t)m * Hsz + hidx;
            const float ig = acc[mi][0][r] + bsv[0];
            const float fg = acc[mi][1][r] + bsv[1];
            const float zg = acc[mi][2][r] + bsv[2];
            const float og = acc[mi][3][r] + bsv[3];
            const float cp = c_prev[off];
            const float mp = m_prev[off];
            const float np = n_prev[off];
            const float zt = tanhf(zg);
            const float ot = 1.f / (1.f + expf(-og));
            const float fm = fg + mp;
            const float mt = fmaxf(fm, ig);
            const float it = expf(ig - mt);
            const float ft = expf(fm - mt);
            const float ct = ft * cp + it * zt;
            const float nt = ft * np + it;
            const float ht = ot * (ct / nt);
            out[off]          = ht;
            out[BH + off]     = ct;
            out[2 * BH + off] = mt;
            out[3 * BH + off] = nt;
        }
    }
}

// ---------------------------------------------------------------------------
extern "C" void kernel_launch(void* const* d_in, const int* in_sizes, int n_in,
                              void* d_out, int out_size, void* d_ws, size_t ws_size,
                              hipStream_t stream) {
    const float* input  = (const float*)d_in[0];
    const float* h_prev = (const float*)d_in[1];
    const float* c_prev = (const float*)d_in[2];
    const float* m_prev = (const float*)d_in[3];
    const float* n_prev = (const float*)d_in[4];
    const float* Wxh    = (const float*)d_in[5];
    const float* bxh    = (const float*)d_in[6];
    const float* Whh    = (const float*)d_in[7];
    const float* bhh    = (const float*)d_in[8];
    float* out = (float*)d_out;

    // Workspace layout: Aq (32 MiB bf16) | Bq (4 MiB bf16) | bias (8 KiB f32)
    __bf16* Aq   = (__bf16*)d_ws;
    __bf16* Bq   = (__bf16*)((char*)d_ws + (size_t)Bsz * Ksz * 2);
    float*  bias = (float*)((char*)d_ws + (size_t)Bsz * Ksz * 2 + (size_t)N4H * Ksz * 2);

    pack_all<<<16384 + 2048, 256, 0, stream>>>(input, h_prev, Wxh, Whh, bxh, bhh,
                                               Aq, Bq, bias);

    // 1-D grid: physical block id drives the XCD-aware remap inside.
    slstm_gemm<<<512, 512, 0, stream>>>(Aq, Bq, bias, c_prev, m_prev, n_prev, out);
}

// Round 3
// 354.941 us; speedup vs baseline: 1.0052x; 1.0052x over previous
//
#include <hip/hip_runtime.h>

// Problem constants
#define Bsz 16384
#define Isz 512
#define Hsz 512
#define Ksz 1024   // I + H
#define N4H 2048   // 4*H

// GEMM tile (256x256, 8-phase schedule)
#define BM 256
#define BN 256
#define BK 64

typedef __bf16 bf16x8 __attribute__((ext_vector_type(8)));
typedef __bf16 bf16x4 __attribute__((ext_vector_type(4)));
typedef float  f32x4  __attribute__((ext_vector_type(4)));

__device__ __forceinline__ void async_copy16(const void* g, void* l) {
    __builtin_amdgcn_global_load_lds(
        (__attribute__((address_space(1))) void*)g,
        (__attribute__((address_space(3))) void*)l,
        16, 0, 0);
}

// ---------------------------------------------------------------------------
// Combined pack kernel (unchanged).
// ---------------------------------------------------------------------------
__global__ void pack_all(const float* __restrict__ x, const float* __restrict__ h,
                         const float* __restrict__ Wxh, const float* __restrict__ Whh,
                         const float* __restrict__ bxh, const float* __restrict__ bhh,
                         __bf16* __restrict__ Aq, __bf16* __restrict__ Bq,
                         float* __restrict__ bias) {
    if (blockIdx.x < 16384) {
        int idx = blockIdx.x * 256 + threadIdx.x;
        int e   = idx << 2;
        int row = e >> 10, col = e & 1023;
        const float4 v = (col < Isz)
            ? *(const float4*)(x + (size_t)row * Isz + col)
            : *(const float4*)(h + (size_t)row * Hsz + (col - Isz));
        bf16x4 o = { (__bf16)v.x, (__bf16)v.y, (__bf16)v.z, (__bf16)v.w };
        *(bf16x4*)(Aq + (size_t)e) = o;
    } else {
        int idx = (blockIdx.x - 16384) * 256 + threadIdx.x;
        int p   = idx >> 8;
        int k   = (idx & 255) << 2;
        int nb  = p >> 7, n = p & 127;
        int wn  = n >> 6, t = (n >> 4) & 3, c = n & 15;
        int orow = t * Hsz + nb * 32 + wn * 16 + c;
        const float4 v = (k < Isz)
            ? *(const float4*)(Wxh + (size_t)orow * Isz + k)
            : *(const float4*)(Whh + (size_t)orow * Hsz + (k - Isz));
        bf16x4 o = { (__bf16)v.x, (__bf16)v.y, (__bf16)v.z, (__bf16)v.w };
        *(bf16x4*)(Bq + (size_t)p * Ksz + k) = o;
        if ((idx & 255) == 0) bias[p] = bxh[orow] + bhh[orow];
    }
}

// ---------------------------------------------------------------------------
// Fused GEMM + sLSTM epilogue — 256x256 tile, 8-wave, 8-phase schedule.
//
// ROUND-3 CHANGE (codegen fix, schedule unchanged from round 1):
//  * Fragment loads are inline-asm ds_read_b128 with offset: immediates.
//    Rounds 1-2 used plain C++ LDS reads; the compiler could not prove they
//    don't alias the global_load_lds LDS writes and inserted s_waitcnt
//    vmcnt(0) drains inside every phase — turning the counted-vmcnt pipeline
//    into a per-phase full-latency stall (observed: MfmaUtil 20/14%, phase
//    cost ~3x budget, mapping-sensitive latency behavior).
//  * s_waitcnt lgkmcnt(0) is followed by sched_barrier(0) (guide rule #18:
//    hipcc hoists register-only MFMA past inline-asm waits otherwise).
//  * Four named __shared__ arrays, no char* buffer arithmetic on writes.
//  * Grid: pid>>3 = bm, pid&7 = nbb (XCD x sees one nbb under round-robin:
//    B-tile L2-resident; A panels streamed once).
//
// vmcnt(4) only at phases 4 and 8: retires exactly the 8 loads (one A+B
// buffer pair) read in the next half-iteration; 4 loads stay in flight.
// LDS XOR swizzle: row r group g stored at g^(r&7); staging permutes the
// per-lane global SOURCE group (gload_lds dest stays linear).
// ---------------------------------------------------------------------------
#define CFENCE asm volatile("" ::: "memory")
#define BARRIER { CFENCE; __builtin_amdgcn_s_barrier(); CFENCE; }
#define WAITLGKM { asm volatile("s_waitcnt lgkmcnt(0)" ::: "memory"); \
                   __builtin_amdgcn_sched_barrier(0); }
#define WAITVM4  asm volatile("s_waitcnt vmcnt(4)" ::: "memory")

// LDS byte address (32-bit) of a pointer into a __shared__ array.
#define LDSA(p) ((unsigned)(size_t)(const __bf16 __attribute__((address_space(3)))*)(p))

#define DSR(dst, addr, IMM) \
    asm volatile("ds_read_b128 %0, %1 offset:" IMM : "=v"(dst) : "v"(addr))

// A fragments: af[f][kk] <- rows (fbase+f)*16 above base, k-group kk.
#define LDS_A_(ap, I0, I1, I2, I3) { \
    const unsigned a0_ = LDSA((ap) + ko0), a1_ = LDSA((ap) + ko1); \
    DSR(af[0][0], a0_, I0); DSR(af[0][1], a1_, I0); \
    DSR(af[1][0], a0_, I1); DSR(af[1][1], a1_, I1); \
    DSR(af[2][0], a0_, I2); DSR(af[2][1], a1_, I2); \
    DSR(af[3][0], a0_, I3); DSR(af[3][1], a1_, I3); }
#define LDS_A0(ap) LDS_A_(ap, "0", "2048", "4096", "6144")
#define LDS_A4(ap) LDS_A_(ap, "8192", "10240", "12288", "14336")

#define LDS_B0(bp) { \
    const unsigned b0_ = LDSA((bp) + ko0), b1_ = LDSA((bp) + ko1); \
    DSR(bf[0][0], b0_, "0");    DSR(bf[0][1], b1_, "0"); \
    DSR(bf[1][0], b0_, "2048"); DSR(bf[1][1], b1_, "2048"); }
#define LDS_B2(bp) { \
    const unsigned b0_ = LDSA((bp) + ko0), b1_ = LDSA((bp) + ko1); \
    DSR(bf[2][0], b0_, "4096"); DSR(bf[2][1], b1_, "4096"); \
    DSR(bf[3][0], b0_, "6144"); DSR(bf[3][1], b1_, "6144"); }

#define MMA(fbase, nbase)                                                     \
    __builtin_amdgcn_s_setprio(1);                                            \
    _Pragma("unroll") for (int f = 0; f < 4; ++f)                             \
    _Pragma("unroll") for (int n = 0; n < 2; ++n)                             \
    _Pragma("unroll") for (int kk = 0; kk < 2; ++kk)                          \
        acc[(fbase) + f][(nbase) + n] = __builtin_amdgcn_mfma_f32_16x16x32_bf16( \
            af[f][kk], bf[(nbase) + n][kk], acc[(fbase) + f][(nbase) + n], 0, 0, 0); \
    __builtin_amdgcn_s_setprio(0);

// One half-tile = 128 rows x 64 cols bf16 = 16 KiB = 2 gload_lds / thread.
#define STAGE(dst, src, half, step)                                           \
    { async_copy16((src) + (size_t)((half) * 128 + rrow) * Ksz + (step) * 64 + scol, \
                   (char*)(dst) + (half) * 16384 + tid * 16);                 \
      async_copy16((src) + (size_t)((half) * 128 + 64 + rrow) * Ksz + (step) * 64 + scol, \
                   (char*)(dst) + (half) * 16384 + 8192 + tid * 16); }

__global__ __launch_bounds__(512, 2) void slstm_gemm(
    const __bf16* __restrict__ Aq, const __bf16* __restrict__ Bq,
    const float* __restrict__ bias,
    const float* __restrict__ c_prev, const float* __restrict__ m_prev,
    const float* __restrict__ n_prev, float* __restrict__ out) {

    __shared__ __bf16 As0[BM * BK];   // 32 KiB each, 128 KiB total
    __shared__ __bf16 As1[BM * BK];
    __shared__ __bf16 Bs0[BN * BK];
    __shared__ __bf16 Bs1[BN * BK];

    const int tid  = threadIdx.x;
    const int w    = tid >> 6;
    const int lane = tid & 63;
    const int wm   = w & 1;          // wave M row (0..1) -> 128 rows each
    const int wc   = w >> 1;         // wave N col (0..3) -> 64 cols each

    const int pid = blockIdx.x;
    const int bm  = pid >> 3;        // batch tile (0..63)
    const int nbb = pid & 7;         // 256-wide gate-col tile (0..7)

    const int lr = lane & 15;
    const int g0 = lane >> 4;        // 0..3
    const int px = lr & 7;

    const __bf16* Ag = Aq + (size_t)bm  * BM * Ksz;
    const __bf16* Bg = Bq + (size_t)nbb * BN * Ksz;

    // staging geometry
    const int rrow = tid >> 3;                    // 0..63
    const int scol = ((tid & 7) ^ (rrow & 7)) * 8;

    // fragment-read bases (swizzled k-group offsets; row&7 == lr&7 always)
    const __bf16* A0p = &As0[(wm * 128 + lr) * 64];
    const __bf16* A1p = &As1[(wm * 128 + lr) * 64];
    const __bf16* B0p = &Bs0[(wc * 64 + lr) * 64];
    const __bf16* B1p = &Bs1[(wc * 64 + lr) * 64];
    const int ko0 = ((0 * 4 + g0) ^ px) * 8;
    const int ko1 = ((1 * 4 + g0) ^ px) * 8;

    f32x4 acc[8][4];
    const f32x4 zero = {0.f, 0.f, 0.f, 0.f};
#pragma unroll
    for (int mi = 0; mi < 8; ++mi)
#pragma unroll
        for (int ni = 0; ni < 4; ++ni) acc[mi][ni] = zero;

    // ---------------- prologue: stage b0 step0 fully + B(b1) step1 ----------
    STAGE(Bs0, Bg, 0, 0);
    STAGE(Bs0, Bg, 1, 0);
    STAGE(As0, Ag, 0, 0);
    STAGE(As0, Ag, 1, 0);
    STAGE(Bs1, Bg, 0, 1);
    STAGE(Bs1, Bg, 1, 1);
    WAITVM4;            // b0 step0 complete; B(b1) step1 (4 loads) in flight
    BARRIER;

    bf16x8 af[4][2];
    bf16x8 bf[4][2];

#pragma unroll 1
    for (int i = 0; i < 8; ++i) {
        const int ic  = (i < 7) ? i : 6;
        const int sA1 = 2 * i + 1;       // A(b1) for this iteration's odd step
        const int sB0 = 2 * ic + 2;      // next even step into b0 (clamped)
        const int sB1 = 2 * ic + 3;      // next odd step into b1 (clamped)

        // ---- p0 (b0, quad 0,0): read A[0..3], B[0..1] ----
        LDS_A0(A0p);
        LDS_B0(B0p);
        STAGE(As1, Ag, 0, sA1);
        BARRIER; WAITLGKM;
        MMA(0, 0);
        BARRIER;

        // ---- p1 (b0, quad 0,1): read B[2..3] ----
        LDS_B2(B0p);
        STAGE(As1, Ag, 1, sA1);
        BARRIER; WAITLGKM;
        MMA(0, 2);
        BARRIER;

        // ---- p2 (b0, quad 1,1): read A[4..7] ----
        LDS_A4(A0p);
        STAGE(Bs0, Bg, 0, sB0);
        BARRIER; WAITLGKM;
        MMA(4, 2);
        BARRIER;

        // ---- p3 (b0, quad 1,0): no reads (bf[0..1] live from p0) ----
        STAGE(Bs0, Bg, 1, sB0);
        BARRIER;
        MMA(4, 0);
        WAITVM4;         // A/B(b1) step 2i+1 complete; p2+p3 stages in flight
        BARRIER;

        // ---- p4 (b1, quad 0,0) ----
        LDS_A0(A1p);
        LDS_B0(B1p);
        STAGE(As0, Ag, 0, sB0);
        BARRIER; WAITLGKM;
        MMA(0, 0);
        BARRIER;

        // ---- p5 (b1, quad 0,1) ----
        LDS_B2(B1p);
        STAGE(As0, Ag, 1, sB0);
        BARRIER; WAITLGKM;
        MMA(0, 2);
        BARRIER;

        // ---- p6 (b1, quad 1,1) ----
        LDS_A4(A1p);
        STAGE(Bs1, Bg, 0, sB1);
        BARRIER; WAITLGKM;
        MMA(4, 2);
        BARRIER;

        // ---- p7 (b1, quad 1,0) ----
        STAGE(Bs1, Bg, 1, sB1);
        BARRIER;
        MMA(4, 0);
        WAITVM4;         // b0 step 2i+2 complete; p6+p7 stages in flight
        BARRIER;
    }

    // ---------------- fused sLSTM epilogue ----------------
    // Wave wc's 4 N-fragments are the 4 gates of the same 16 h values.
    const int hidx = (nbb * 2 + (wc >> 1)) * 32 + (wc & 1) * 16 + lr;

    float bsv[4];
#pragma unroll
    for (int n = 0; n < 4; ++n)
        bsv[n] = bias[nbb * 256 + wc * 64 + n * 16 + lr];

    const size_t BH = (size_t)Bsz * Hsz;

#pragma unroll
    for (int mi = 0; mi < 8; ++mi) {
        const int mbase = bm * 256 + wm * 128 + mi * 16 + g0 * 4;
#pragma unroll
        for (int r = 0; r < 4; ++r) {
            const int m = mbase + r;
            const size_t off = (size_t)m * Hsz + hidx;
            const float ig = acc[mi][0][r] + bsv[0];
            const float fg = acc[mi][1][r] + bsv[1];
            const float zg = acc[mi][2][r] + bsv[2];
            const float og = acc[mi][3][r] + bsv[3];
            const float cp = c_prev[off];
            const float mp = m_prev[off];
            const float np = n_prev[off];
            const float zt = tanhf(zg);
            const float ot = 1.f / (1.f + expf(-og));
            const float fm = fg + mp;
            const float mt = fmaxf(fm, ig);
            const float it = expf(ig - mt);
            const float ft = expf(fm - mt);
            const float ct = ft * cp + it * zt;
            const float nt = ft * np + it;
            const float ht = ot * (ct / nt);
            out[off]          = ht;
            out[BH + off]     = ct;
            out[2 * BH + off] = mt;
            out[3 * BH + off] = nt;
        }
    }
}

// ---------------------------------------------------------------------------
extern "C" void kernel_launch(void* const* d_in, const int* in_sizes, int n_in,
                              void* d_out, int out_size, void* d_ws, size_t ws_size,
                              hipStream_t stream) {
    const float* input  = (const float*)d_in[0];
    const float* h_prev = (const float*)d_in[1];
    const float* c_prev = (const float*)d_in[2];
    const float* m_prev = (const float*)d_in[3];
    const float* n_prev = (const float*)d_in[4];
    const float* Wxh    = (const float*)d_in[5];
    const float* bxh    = (const float*)d_in[6];
    const float* Whh    = (const float*)d_in[7];
    const float* bhh    = (const float*)d_in[8];
    float* out = (float*)d_out;

    // Workspace layout: Aq (32 MiB bf16) | Bq (4 MiB bf16) | bias (8 KiB f32)
    __bf16* Aq   = (__bf16*)d_ws;
    __bf16* Bq   = (__bf16*)((char*)d_ws + (size_t)Bsz * Ksz * 2);
    float*  bias = (float*)((char*)d_ws + (size_t)Bsz * Ksz * 2 + (size_t)N4H * Ksz * 2);

    pack_all<<<16384 + 2048, 256, 0, stream>>>(input, h_prev, Wxh, Whh, bxh, bhh,
                                               Aq, Bq, bias);

    slstm_gemm<<<512, 512, 0, stream>>>(Aq, Bq, bias, c_prev, m_prev, n_prev, out);
}

// Round 4
// 344.232 us; speedup vs baseline: 1.0365x; 1.0311x over previous
//
#include <hip/hip_runtime.h>

// Problem constants
#define Bsz 16384
#define Isz 512
#define Hsz 512
#define Ksz 1024   // I + H
#define N4H 2048   // 4*H

// GEMM tile
#define BM 128
#define BK 64

typedef __bf16 bf16x8 __attribute__((ext_vector_type(8)));
typedef __bf16 bf16x4 __attribute__((ext_vector_type(4)));
typedef float  f32x4  __attribute__((ext_vector_type(4)));

__device__ __forceinline__ void async_copy16(const void* g, void* l) {
    __builtin_amdgcn_global_load_lds(
        (__attribute__((address_space(1))) void*)g,
        (__attribute__((address_space(3))) void*)l,
        16, 0, 0);
}

// ---------------------------------------------------------------------------
// Combined pack kernel (identical to round 0).
// Blocks [0, 16384): activations  Aq[b][k] = bf16([input|h_prev][b][k])
// Blocks [16384, 18432): weights with gate-interleaved row permutation +
//   fused bias.  Permuted row p: nb=p/128, n=p%128; wn=n>>6, gate=(n>>4)&3,
//   c=n&15 -> original row = gate*512 + nb*32 + wn*16 + c.
// ---------------------------------------------------------------------------
__global__ void pack_all(const float* __restrict__ x, const float* __restrict__ h,
                         const float* __restrict__ Wxh, const float* __restrict__ Whh,
                         const float* __restrict__ bxh, const float* __restrict__ bhh,
                         __bf16* __restrict__ Aq, __bf16* __restrict__ Bq,
                         float* __restrict__ bias) {
    if (blockIdx.x < 16384) {
        int idx = blockIdx.x * 256 + threadIdx.x;
        int e   = idx << 2;                 // 4 elements per thread
        int row = e >> 10, col = e & 1023;  // col multiple of 4, never straddles 512
        const float4 v = (col < Isz)
            ? *(const float4*)(x + (size_t)row * Isz + col)
            : *(const float4*)(h + (size_t)row * Hsz + (col - Isz));
        bf16x4 o = { (__bf16)v.x, (__bf16)v.y, (__bf16)v.z, (__bf16)v.w };
        *(bf16x4*)(Aq + (size_t)e) = o;
    } else {
        int idx = (blockIdx.x - 16384) * 256 + threadIdx.x;
        int p   = idx >> 8;            // permuted row, 256 k-groups per row
        int k   = (idx & 255) << 2;
        int nb  = p >> 7, n = p & 127;
        int wn  = n >> 6, t = (n >> 4) & 3, c = n & 15;
        int orow = t * Hsz + nb * 32 + wn * 16 + c;
        const float4 v = (k < Isz)
            ? *(const float4*)(Wxh + (size_t)orow * Isz + k)
            : *(const float4*)(Whh + (size_t)orow * Hsz + (k - Isz));
        bf16x4 o = { (__bf16)v.x, (__bf16)v.y, (__bf16)v.z, (__bf16)v.w };
        *(bf16x4*)(Bq + (size_t)p * Ksz + k) = o;
        if ((idx & 255) == 0) bias[p] = bxh[orow] + bhh[orow];
    }
}

// ---------------------------------------------------------------------------
// Fused GEMM + sLSTM epilogue — ROUND-0 STRUCTURE (best measured: 127.4 us),
// reverted after the 8-phase 256^2 line failed its kill-switch (rounds 1-3:
// 139/192/145 us, MfmaUtil stuck ~20% vs round-0's 127 us @ 22%).
//
// ROUND-4 CHANGE (epilogue only): hardware transcendentals.
// Round-0 used libm tanhf/expf/fdiv (~90 VALU-ops/element; 8.4M elements
// ~= 38 us of VALU — matches measured VALUBusy 32%). Replaced with
// v_exp_f32 / v_rcp_f32 via __builtin_amdgcn_exp2f / __builtin_amdgcn_rcpf
// (~28 ops/element). Saturation-safe forms:
//   sigmoid(x) = rcp(1 + exp2(-x*log2e))            (x->-inf: 0, x->inf: 1)
//   tanh(x)    = 1 - 2*rcp(exp2(2x*log2e) + 1)      (limits +-1, no inf*0)
//   exp(x)     = exp2(x*log2e)                      (args <= 0 here)
// Error ~1e-6 rel vs libm — negligible against bf16-GEMM absmax 0.03125.
//
// Block: 256 threads = 4 waves in 2x2; each wave owns a 64x64 sub-tile
// (4x4 of 16x16x32 MFMA). Block tile: 128 rows (batch) x 128 cols
// (= 4 gates x 32 h). Grid: (16384/128, 512/32) = (128, 16).
//
// LDS layout is XOR-swizzled to kill ds_read_b128 bank conflicts:
// row r's 16-B group g is stored at group position g^(r&7). Staging keeps the
// HW-mandated dest = base + lane*16 and instead permutes each lane's global
// SOURCE group; fragment reads apply p = g ^ (r&7).
// ---------------------------------------------------------------------------
__global__ __launch_bounds__(256, 4) void slstm_gemm(
    const __bf16* __restrict__ Aq, const __bf16* __restrict__ Bq,
    const float* __restrict__ bias,
    const float* __restrict__ c_prev, const float* __restrict__ m_prev,
    const float* __restrict__ n_prev, float* __restrict__ out) {

    __shared__ __bf16 As[BM * BK];   // 16 KiB
    __shared__ __bf16 Bs[BM * BK];   // 16 KiB

    const int tid  = threadIdx.x;
    const int w    = tid >> 6;
    const int lane = tid & 63;
    const int wm   = w & 1;          // wave row (0..1)
    const int wn   = w >> 1;         // wave col (0..1)
    const int bm   = blockIdx.x;     // batch tile
    const int nb   = blockIdx.y;     // h tile (32 h per block)

    const __bf16* Ag = Aq + (size_t)bm * BM * Ksz;
    const __bf16* Bg = Bq + (size_t)nb * BM * Ksz;   // 128 permuted weight rows

    f32x4 acc[4][4];
    const f32x4 zero = {0.f, 0.f, 0.f, 0.f};
#pragma unroll
    for (int mi = 0; mi < 4; ++mi)
#pragma unroll
        for (int ni = 0; ni < 4; ++ni) acc[mi][ni] = zero;

    // Staging geometry: 16 chunks of 1024 B per tile (8 rows each); wave w
    // owns chunks w*4 .. w*4+3. Lane L covers row chunk*8 + (L>>3); its LDS
    // slot is within-row group position L&7, which (swizzled) must hold
    // global group (L&7) ^ ((L>>3)&7).
    const int srow = (lane >> 3);
    const int scol = ((lane & 7) ^ srow) * 8;     // swizzled source, in elements

    for (int k0 = 0; k0 < Ksz; k0 += BK) {
        __syncthreads();   // previous iteration's compute done before overwrite
#pragma unroll
        for (int i = 0; i < 4; ++i) {
            const int chunk = w * 4 + i;
            const int row   = chunk * 8 + srow;
            async_copy16(Ag + (size_t)row * Ksz + k0 + scol, (char*)As + chunk * 1024);
            async_copy16(Bg + (size_t)row * Ksz + k0 + scol, (char*)Bs + chunk * 1024);
        }
        __syncthreads();   // implicit vmcnt(0) drain completes the LDS fills

#pragma unroll
        for (int kk = 0; kk < 2; ++kk) {
            bf16x8 af[4], bf[4];
#pragma unroll
            for (int mi = 0; mi < 4; ++mi) {
                const int r = wm * 64 + mi * 16 + (lane & 15);
                const int p = (kk * 4 + (lane >> 4)) ^ (r & 7);
                af[mi] = *(const bf16x8*)(As + r * BK + p * 8);
            }
#pragma unroll
            for (int ni = 0; ni < 4; ++ni) {
                const int r = wn * 64 + ni * 16 + (lane & 15);
                const int p = (kk * 4 + (lane >> 4)) ^ (r & 7);
                bf[ni] = *(const bf16x8*)(Bs + r * BK + p * 8);
            }
#pragma unroll
            for (int mi = 0; mi < 4; ++mi)
#pragma unroll
                for (int ni = 0; ni < 4; ++ni)
                    acc[mi][ni] = __builtin_amdgcn_mfma_f32_16x16x32_bf16(
                        af[mi], bf[ni], acc[mi][ni], 0, 0, 0);
        }
    }

    // ---------------- fused sLSTM epilogue (fast-math version) ----------------
    // Lane's h is shared by all 4 column-tiles (ni == gate index).
    const int hidx = nb * 32 + wn * 16 + (lane & 15);
    const int quad = lane >> 4;

    float bsv[4];
#pragma unroll
    for (int ni = 0; ni < 4; ++ni)
        bsv[ni] = bias[nb * 128 + wn * 64 + ni * 16 + (lane & 15)];

    const size_t BH = (size_t)Bsz * Hsz;
    const float L2E  = 1.44269504089f;   // log2(e)
    const float L2E2 = 2.88539008178f;   // 2*log2(e)

#pragma unroll
    for (int mi = 0; mi < 4; ++mi) {
        const int mbase = bm * 128 + wm * 64 + mi * 16 + quad * 4;
#pragma unroll
        for (int r = 0; r < 4; ++r) {
            const int m = mbase + r;
            const size_t off = (size_t)m * Hsz + hidx;
            const float ig = acc[mi][0][r] + bsv[0];
            const float fg = acc[mi][1][r] + bsv[1];
            const float zg = acc[mi][2][r] + bsv[2];
            const float og = acc[mi][3][r] + bsv[3];
            const float cp = c_prev[off];
            const float mp = m_prev[off];
            const float np = n_prev[off];
            // tanh(zg) = 1 - 2/(exp2(2*zg*log2e)+1)  (saturates to +-1 cleanly)
            const float zt = 1.f - 2.f * __builtin_amdgcn_rcpf(
                                 __builtin_amdgcn_exp2f(zg * L2E2) + 1.f);
            // sigmoid(og) = 1/(1+exp2(-og*log2e))
            const float ot = __builtin_amdgcn_rcpf(
                                 __builtin_amdgcn_exp2f(-og * L2E) + 1.f);
            const float fm = fg + mp;
            const float mt = fmaxf(fm, ig);
            const float it = __builtin_amdgcn_exp2f((ig - mt) * L2E);
            const float ft = __builtin_amdgcn_exp2f((fm - mt) * L2E);
            const float ct = ft * cp + it * zt;
            const float nt = ft * np + it;
            const float ht = ot * ct * __builtin_amdgcn_rcpf(nt);
            out[off]          = ht;
            out[BH + off]     = ct;
            out[2 * BH + off] = mt;
            out[3 * BH + off] = nt;
        }
    }
}

// ---------------------------------------------------------------------------
extern "C" void kernel_launch(void* const* d_in, const int* in_sizes, int n_in,
                              void* d_out, int out_size, void* d_ws, size_t ws_size,
                              hipStream_t stream) {
    const float* input  = (const float*)d_in[0];
    const float* h_prev = (const float*)d_in[1];
    const float* c_prev = (const float*)d_in[2];
    const float* m_prev = (const float*)d_in[3];
    const float* n_prev = (const float*)d_in[4];
    const float* Wxh    = (const float*)d_in[5];
    const float* bxh    = (const float*)d_in[6];
    const float* Whh    = (const float*)d_in[7];
    const float* bhh    = (const float*)d_in[8];
    float* out = (float*)d_out;

    // Workspace layout: Aq (32 MiB bf16) | Bq (4 MiB bf16) | bias (8 KiB f32)
    __bf16* Aq   = (__bf16*)d_ws;
    __bf16* Bq   = (__bf16*)((char*)d_ws + (size_t)Bsz * Ksz * 2);
    float*  bias = (float*)((char*)d_ws + (size_t)Bsz * Ksz * 2 + (size_t)N4H * Ksz * 2);

    // 16384 activation blocks + 2048 weight blocks in one launch
    pack_all<<<16384 + 2048, 256, 0, stream>>>(input, h_prev, Wxh, Whh, bxh, bhh,
                                               Aq, Bq, bias);

    dim3 grid(Bsz / BM, Hsz / 32);
    slstm_gemm<<<grid, 256, 0, stream>>>(Aq, Bq, bias, c_prev, m_prev, n_prev, out);
}

// Round 5
// 329.043 us; speedup vs baseline: 1.0844x; 1.0462x over previous
//
#include <hip/hip_runtime.h>

// Problem constants
#define Bsz 16384
#define Isz 512
#define Hsz 512
#define Ksz 1024   // I + H
#define N4H 2048   // 4*H

// GEMM tile (256x256, 8-phase schedule)
#define BM 256
#define BN 256
#define BK 64

typedef __bf16 bf16x8 __attribute__((ext_vector_type(8)));
typedef __bf16 bf16x4 __attribute__((ext_vector_type(4)));
typedef float  f32x4  __attribute__((ext_vector_type(4)));

__device__ __forceinline__ void async_copy16(const void* g, void* l) {
    __builtin_amdgcn_global_load_lds(
        (__attribute__((address_space(1))) void*)g,
        (__attribute__((address_space(3))) void*)l,
        16, 0, 0);
}

// ---------------------------------------------------------------------------
// Combined pack kernel (unchanged).
// ---------------------------------------------------------------------------
__global__ void pack_all(const float* __restrict__ x, const float* __restrict__ h,
                         const float* __restrict__ Wxh, const float* __restrict__ Whh,
                         const float* __restrict__ bxh, const float* __restrict__ bhh,
                         __bf16* __restrict__ Aq, __bf16* __restrict__ Bq,
                         float* __restrict__ bias) {
    if (blockIdx.x < 16384) {
        int idx = blockIdx.x * 256 + threadIdx.x;
        int e   = idx << 2;
        int row = e >> 10, col = e & 1023;
        const float4 v = (col < Isz)
            ? *(const float4*)(x + (size_t)row * Isz + col)
            : *(const float4*)(h + (size_t)row * Hsz + (col - Isz));
        bf16x4 o = { (__bf16)v.x, (__bf16)v.y, (__bf16)v.z, (__bf16)v.w };
        *(bf16x4*)(Aq + (size_t)e) = o;
    } else {
        int idx = (blockIdx.x - 16384) * 256 + threadIdx.x;
        int p   = idx >> 8;
        int k   = (idx & 255) << 2;
        int nb  = p >> 7, n = p & 127;
        int wn  = n >> 6, t = (n >> 4) & 3, c = n & 15;
        int orow = t * Hsz + nb * 32 + wn * 16 + c;
        const float4 v = (k < Isz)
            ? *(const float4*)(Wxh + (size_t)orow * Isz + k)
            : *(const float4*)(Whh + (size_t)orow * Hsz + (k - Isz));
        bf16x4 o = { (__bf16)v.x, (__bf16)v.y, (__bf16)v.z, (__bf16)v.w };
        *(bf16x4*)(Bq + (size_t)p * Ksz + k) = o;
        if ((idx & 255) == 0) bias[p] = bxh[orow] + bhh[orow];
    }
}

// ---------------------------------------------------------------------------
// Fused GEMM + sLSTM epilogue — 256x256 tile, 8-wave, 8-phase schedule.
//
// ROUND-5: the deconfounded experiment. Round 3 changed codegen (inline-asm
// ds_read + counted waits) AND block mapping together; its +86 MB FETCH
// regression came from the mapping alone. This round keeps round-3 codegen
// byte-identical but reverts to round-1's plain 2-D grid (64,8) mapping,
// which measured compulsory-only FETCH (98.6 MB = staging fully L2/L3-hit).
// Also ports round-4's verified fast-math epilogue.
//
// Schedule: per phase {inline-asm ds_read_b128 subtile | issue 1 half-tile
// global_load_lds} -> barrier -> lgkmcnt(0)+sched_barrier(0) -> setprio(1)
// -> 16 MFMA -> setprio(0) -> barrier. vmcnt(4) ONLY at phases 4 and 8:
// retires exactly the 8 loads (one A+B buffer pair) read next; 4 stay in
// flight across barriers. WAR-safety: every restage of a buffer region is
// issued after the double barrier following that region's last ds_read
// (verified phase-by-phase; harness-passed in round 3).
// LDS XOR swizzle: row r group g stored at g^(r&7); staging permutes the
// per-lane global SOURCE group (gload_lds dest stays linear).
// ---------------------------------------------------------------------------
#define CFENCE asm volatile("" ::: "memory")
#define BARRIER { CFENCE; __builtin_amdgcn_s_barrier(); CFENCE; }
#define WAITLGKM { asm volatile("s_waitcnt lgkmcnt(0)" ::: "memory"); \
                   __builtin_amdgcn_sched_barrier(0); }
#define WAITVM4  asm volatile("s_waitcnt vmcnt(4)" ::: "memory")

// LDS byte address (32-bit) of a pointer into a __shared__ array.
#define LDSA(p) ((unsigned)(size_t)(const __bf16 __attribute__((address_space(3)))*)(p))

#define DSR(dst, addr, IMM) \
    asm volatile("ds_read_b128 %0, %1 offset:" IMM : "=v"(dst) : "v"(addr))

// A fragments: af[f][kk] <- rows (fbase+f)*16 above base, k-group kk.
#define LDS_A_(ap, I0, I1, I2, I3) { \
    const unsigned a0_ = LDSA((ap) + ko0), a1_ = LDSA((ap) + ko1); \
    DSR(af[0][0], a0_, I0); DSR(af[0][1], a1_, I0); \
    DSR(af[1][0], a0_, I1); DSR(af[1][1], a1_, I1); \
    DSR(af[2][0], a0_, I2); DSR(af[2][1], a1_, I2); \
    DSR(af[3][0], a0_, I3); DSR(af[3][1], a1_, I3); }
#define LDS_A0(ap) LDS_A_(ap, "0", "2048", "4096", "6144")
#define LDS_A4(ap) LDS_A_(ap, "8192", "10240", "12288", "14336")

#define LDS_B0(bp) { \
    const unsigned b0_ = LDSA((bp) + ko0), b1_ = LDSA((bp) + ko1); \
    DSR(bf[0][0], b0_, "0");    DSR(bf[0][1], b1_, "0"); \
    DSR(bf[1][0], b0_, "2048"); DSR(bf[1][1], b1_, "2048"); }
#define LDS_B2(bp) { \
    const unsigned b0_ = LDSA((bp) + ko0), b1_ = LDSA((bp) + ko1); \
    DSR(bf[2][0], b0_, "4096"); DSR(bf[2][1], b1_, "4096"); \
    DSR(bf[3][0], b0_, "6144"); DSR(bf[3][1], b1_, "6144"); }

#define MMA(fbase, nbase)                                                     \
    __builtin_amdgcn_s_setprio(1);                                            \
    _Pragma("unroll") for (int f = 0; f < 4; ++f)                             \
    _Pragma("unroll") for (int n = 0; n < 2; ++n)                             \
    _Pragma("unroll") for (int kk = 0; kk < 2; ++kk)                          \
        acc[(fbase) + f][(nbase) + n] = __builtin_amdgcn_mfma_f32_16x16x32_bf16( \
            af[f][kk], bf[(nbase) + n][kk], acc[(fbase) + f][(nbase) + n], 0, 0, 0); \
    __builtin_amdgcn_s_setprio(0);

// One half-tile = 128 rows x 64 cols bf16 = 16 KiB = 2 gload_lds / thread.
#define STAGE(dst, src, half, step)                                           \
    { async_copy16((src) + (size_t)((half) * 128 + rrow) * Ksz + (step) * 64 + scol, \
                   (char*)(dst) + (half) * 16384 + tid * 16);                 \
      async_copy16((src) + (size_t)((half) * 128 + 64 + rrow) * Ksz + (step) * 64 + scol, \
                   (char*)(dst) + (half) * 16384 + 8192 + tid * 16); }

__global__ __launch_bounds__(512, 2) void slstm_gemm(
    const __bf16* __restrict__ Aq, const __bf16* __restrict__ Bq,
    const float* __restrict__ bias,
    const float* __restrict__ c_prev, const float* __restrict__ m_prev,
    const float* __restrict__ n_prev, float* __restrict__ out) {

    __shared__ __bf16 As0[BM * BK];   // 32 KiB each, 128 KiB total
    __shared__ __bf16 As1[BM * BK];
    __shared__ __bf16 Bs0[BN * BK];
    __shared__ __bf16 Bs1[BN * BK];

    const int tid  = threadIdx.x;
    const int w    = tid >> 6;
    const int lane = tid & 63;
    const int wm   = w & 1;          // wave M row (0..1) -> 128 rows each
    const int wc   = w >> 1;         // wave N col (0..3) -> 64 cols each

    // Round-1 mapping (measured compulsory-only FETCH): plain 2-D grid.
    const int bm  = blockIdx.x;      // batch tile (0..63)
    const int nbb = blockIdx.y;      // 256-wide gate-col tile (0..7)

    const int lr = lane & 15;
    const int g0 = lane >> 4;        // 0..3
    const int px = lr & 7;

    const __bf16* Ag = Aq + (size_t)bm  * BM * Ksz;
    const __bf16* Bg = Bq + (size_t)nbb * BN * Ksz;

    // staging geometry
    const int rrow = tid >> 3;                    // 0..63
    const int scol = ((tid & 7) ^ (rrow & 7)) * 8;

    // fragment-read bases (swizzled k-group offsets; row&7 == lr&7 always)
    const __bf16* A0p = &As0[(wm * 128 + lr) * 64];
    const __bf16* A1p = &As1[(wm * 128 + lr) * 64];
    const __bf16* B0p = &Bs0[(wc * 64 + lr) * 64];
    const __bf16* B1p = &Bs1[(wc * 64 + lr) * 64];
    const int ko0 = ((0 * 4 + g0) ^ px) * 8;
    const int ko1 = ((1 * 4 + g0) ^ px) * 8;

    f32x4 acc[8][4];
    const f32x4 zero = {0.f, 0.f, 0.f, 0.f};
#pragma unroll
    for (int mi = 0; mi < 8; ++mi)
#pragma unroll
        for (int ni = 0; ni < 4; ++ni) acc[mi][ni] = zero;

    // ---------------- prologue: stage b0 step0 fully + B(b1) step1 ----------
    STAGE(Bs0, Bg, 0, 0);
    STAGE(Bs0, Bg, 1, 0);
    STAGE(As0, Ag, 0, 0);
    STAGE(As0, Ag, 1, 0);
    STAGE(Bs1, Bg, 0, 1);
    STAGE(Bs1, Bg, 1, 1);
    WAITVM4;            // b0 step0 complete; B(b1) step1 (4 loads) in flight
    BARRIER;

    bf16x8 af[4][2];
    bf16x8 bf[4][2];

#pragma unroll 1
    for (int i = 0; i < 8; ++i) {
        const int ic  = (i < 7) ? i : 6;
        const int sA1 = 2 * i + 1;       // A(b1) for this iteration's odd step
        const int sB0 = 2 * ic + 2;      // next even step into b0 (clamped)
        const int sB1 = 2 * ic + 3;      // next odd step into b1 (clamped)

        // ---- p0 (b0, quad 0,0): read A[0..3], B[0..1] ----
        LDS_A0(A0p);
        LDS_B0(B0p);
        STAGE(As1, Ag, 0, sA1);
        BARRIER; WAITLGKM;
        MMA(0, 0);
        BARRIER;

        // ---- p1 (b0, quad 0,1): read B[2..3] ----
        LDS_B2(B0p);
        STAGE(As1, Ag, 1, sA1);
        BARRIER; WAITLGKM;
        MMA(0, 2);
        BARRIER;

        // ---- p2 (b0, quad 1,1): read A[4..7] ----
        LDS_A4(A0p);
        STAGE(Bs0, Bg, 0, sB0);
        BARRIER; WAITLGKM;
        MMA(4, 2);
        BARRIER;

        // ---- p3 (b0, quad 1,0): no reads (bf[0..1] live from p0) ----
        STAGE(Bs0, Bg, 1, sB0);
        BARRIER;
        MMA(4, 0);
        WAITVM4;         // A/B(b1) step 2i+1 complete; p2+p3 stages in flight
        BARRIER;

        // ---- p4 (b1, quad 0,0) ----
        LDS_A0(A1p);
        LDS_B0(B1p);
        STAGE(As0, Ag, 0, sB0);
        BARRIER; WAITLGKM;
        MMA(0, 0);
        BARRIER;

        // ---- p5 (b1, quad 0,1) ----
        LDS_B2(B1p);
        STAGE(As0, Ag, 1, sB0);
        BARRIER; WAITLGKM;
        MMA(0, 2);
        BARRIER;

        // ---- p6 (b1, quad 1,1) ----
        LDS_A4(A1p);
        STAGE(Bs1, Bg, 0, sB1);
        BARRIER; WAITLGKM;
        MMA(4, 2);
        BARRIER;

        // ---- p7 (b1, quad 1,0) ----
        STAGE(Bs1, Bg, 1, sB1);
        BARRIER;
        MMA(4, 0);
        WAITVM4;         // b0 step 2i+2 complete; p6+p7 stages in flight
        BARRIER;
    }

    // ---------------- fused sLSTM epilogue (fast-math, from round 4) --------
    // Wave wc's 4 N-fragments are the 4 gates of the same 16 h values.
    const int hidx = (nbb * 2 + (wc >> 1)) * 32 + (wc & 1) * 16 + lr;

    float bsv[4];
#pragma unroll
    for (int n = 0; n < 4; ++n)
        bsv[n] = bias[nbb * 256 + wc * 64 + n * 16 + lr];

    const size_t BH = (size_t)Bsz * Hsz;
    const float L2E  = 1.44269504089f;   // log2(e)
    const float L2E2 = 2.88539008178f;   // 2*log2(e)

#pragma unroll
    for (int mi = 0; mi < 8; ++mi) {
        const int mbase = bm * 256 + wm * 128 + mi * 16 + g0 * 4;
#pragma unroll
        for (int r = 0; r < 4; ++r) {
            const int m = mbase + r;
            const size_t off = (size_t)m * Hsz + hidx;
            const float ig = acc[mi][0][r] + bsv[0];
            const float fg = acc[mi][1][r] + bsv[1];
            const float zg = acc[mi][2][r] + bsv[2];
            const float og = acc[mi][3][r] + bsv[3];
            const float cp = c_prev[off];
            const float mp = m_prev[off];
            const float np = n_prev[off];
            // tanh(zg) = 1 - 2/(exp2(2*zg*log2e)+1)  (saturates to +-1 cleanly)
            const float zt = 1.f - 2.f * __builtin_amdgcn_rcpf(
                                 __builtin_amdgcn_exp2f(zg * L2E2) + 1.f);
            // sigmoid(og) = 1/(1+exp2(-og*log2e))
            const float ot = __builtin_amdgcn_rcpf(
                                 __builtin_amdgcn_exp2f(-og * L2E) + 1.f);
            const float fm = fg + mp;
            const float mt = fmaxf(fm, ig);
            const float it = __builtin_amdgcn_exp2f((ig - mt) * L2E);
            const float ft = __builtin_amdgcn_exp2f((fm - mt) * L2E);
            const float ct = ft * cp + it * zt;
            const float nt = ft * np + it;
            const float ht = ot * ct * __builtin_amdgcn_rcpf(nt);
            out[off]          = ht;
            out[BH + off]     = ct;
            out[2 * BH + off] = mt;
            out[3 * BH + off] = nt;
        }
    }
}

// ---------------------------------------------------------------------------
extern "C" void kernel_launch(void* const* d_in, const int* in_sizes, int n_in,
                              void* d_out, int out_size, void* d_ws, size_t ws_size,
                              hipStream_t stream) {
    const float* input  = (const float*)d_in[0];
    const float* h_prev = (const float*)d_in[1];
    const float* c_prev = (const float*)d_in[2];
    const float* m_prev = (const float*)d_in[3];
    const float* n_prev = (const float*)d_in[4];
    const float* Wxh    = (const float*)d_in[5];
    const float* bxh    = (const float*)d_in[6];
    const float* Whh    = (const float*)d_in[7];
    const float* bhh    = (const float*)d_in[8];
    float* out = (float*)d_out;

    // Workspace layout: Aq (32 MiB bf16) | Bq (4 MiB bf16) | bias (8 KiB f32)
    __bf16* Aq   = (__bf16*)d_ws;
    __bf16* Bq   = (__bf16*)((char*)d_ws + (size_t)Bsz * Ksz * 2);
    float*  bias = (float*)((char*)d_ws + (size_t)Bsz * Ksz * 2 + (size_t)N4H * Ksz * 2);

    pack_all<<<16384 + 2048, 256, 0, stream>>>(input, h_prev, Wxh, Whh, bxh, bhh,
                                               Aq, Bq, bias);

    dim3 grid(Bsz / BM, N4H / BN);
    slstm_gemm<<<grid, 512, 0, stream>>>(Aq, Bq, bias, c_prev, m_prev, n_prev, out);
}